// Round 6
// baseline (434.980 us; speedup 1.0000x reference)
//
#include <hip/hip_runtime.h>
#include <math.h>
#include <stdint.h>

#define NTOT   8192
#define HALF_N 4096
#define DIM    512
#define INV_T  14.2857142857142857f   // 1/0.07
#define NBLK   2080                   // triangular 64x64 grid

using s16x8 = __attribute__((ext_vector_type(8))) short;
using f32x4 = __attribute__((ext_vector_type(4))) float;

// Scratch in static device globals (fully rewritten every call; no d_ws use).
__device__ unsigned short g_fnb[NTOT * DIM];   // normalized bf16 matrix, 8 MB
__device__ float g_pos[NTOT];
__device__ float g_sumexp[NTOT];
__device__ int   g_cnt[NTOT];
__device__ int   g_done;                        // last-block-finalize counter

__device__ __forceinline__ float bf2f(unsigned short u) {
  union { unsigned int i; float f; } v; v.i = ((unsigned int)u) << 16; return v.f;
}
__device__ __forceinline__ unsigned short f2bf(float x) {
  union { float f; unsigned int i; } v; v.f = x;
  unsigned int u = v.i;
  return (unsigned short)((u + 0x7FFFu + ((u >> 16) & 1u)) >> 16);
}

// ---------------- kernel 1: normalize pairs -> bf16, pos, zero stats ----------------
// 256 threads = 2 pairs. Within a pair: first wave = row b (f1), second = b+4096 (f2).
__global__ __launch_bounds__(256) void knorm(const float* __restrict__ f1,
                                             const float* __restrict__ f2) {
  const int tid  = threadIdx.x;
  const int wv   = tid >> 6;
  const int pi   = wv >> 1;            // pair within block
  const int half = wv & 1;             // 0: f1 row, 1: f2 row
  const int lane = tid & 63;
  const int b    = blockIdx.x * 2 + pi;
  const int row  = b + half * HALF_N;

  if (blockIdx.x == 0 && tid == 0) g_done = 0;
  if (tid < 4) {                       // zero the 4 stat rows this block owns
    const int r = blockIdx.x * 2 + (tid & 1) + (tid >> 1) * HALF_N;
    g_sumexp[r] = 0.f; g_cnt[r] = 0;
  }

  const float* src = (half == 0) ? (f1 + (size_t)b * DIM) : (f2 + (size_t)b * DIM);
  float4 v0 = ((const float4*)src)[lane];
  float4 v1 = ((const float4*)src)[lane + 64];
  float ss = v0.x*v0.x + v0.y*v0.y + v0.z*v0.z + v0.w*v0.w
           + v1.x*v1.x + v1.y*v1.y + v1.z*v1.z + v1.w*v1.w;
  #pragma unroll
  for (int o = 32; o >= 1; o >>= 1) ss += __shfl_xor(ss, o, 64);
  const float sc = 1.0f / fmaxf(sqrtf(ss), 1e-8f);
  ushort4 h0, h1;
  h0.x = f2bf(v0.x * sc); h0.y = f2bf(v0.y * sc);
  h0.z = f2bf(v0.z * sc); h0.w = f2bf(v0.w * sc);
  h1.x = f2bf(v1.x * sc); h1.y = f2bf(v1.y * sc);
  h1.z = f2bf(v1.z * sc); h1.w = f2bf(v1.w * sc);
  ushort4* dst = (ushort4*)(g_fnb + (size_t)row * DIM);
  dst[lane]      = h0;
  dst[lane + 64] = h1;

  // pos[b] = <fn_b, fn_{b+4096}> on the same bf16 values the GEMM uses
  __shared__ ushort4 sh[2][64][2];
  if (half == 1) { sh[pi][lane][0] = h0; sh[pi][lane][1] = h1; }
  __syncthreads();
  if (half == 0) {
    const ushort4 p0 = sh[pi][lane][0], p1 = sh[pi][lane][1];
    float s = bf2f(h0.x)*bf2f(p0.x) + bf2f(h0.y)*bf2f(p0.y)
            + bf2f(h0.z)*bf2f(p0.z) + bf2f(h0.w)*bf2f(p0.w)
            + bf2f(h1.x)*bf2f(p1.x) + bf2f(h1.y)*bf2f(p1.y)
            + bf2f(h1.z)*bf2f(p1.z) + bf2f(h1.w)*bf2f(p1.w);
    #pragma unroll
    for (int o = 32; o >= 1; o >>= 1) s += __shfl_xor(s, o, 64);
    if (lane == 0) { g_pos[b] = s; g_pos[b + HALF_N] = s; }
  }
}

// ---------------- kernel 2: barrier-free symmetric GEMM + reductions + finalize ----
// Upper triangle only (bi <= bj), 2080 blocks. NO LDS, NO barriers in the K-loop:
// each wave loads MFMA fragments directly from global (L2/L3-resident 8 MB table),
// distance-1 register prefetch so loads for step s+1 fly under step s's MFMAs.
// Off-diagonal tiles feed row stats (i) AND col stats (j).
// Last block to finish folds the final 4-scalar reduction (device-scope loads).
__global__ __launch_bounds__(256, 3) void kmain(float* __restrict__ out) {
  // triangular decode: blockIdx -> (bi, bj), bi <= bj
  int t = blockIdx.x;
  int bi = 0, rem = 64;
  while (t >= rem) { t -= rem; --rem; ++bi; }
  const int bj = bi + t;
  const bool offdiag = (bi != bj);
  const int i0 = bi * 128, j0 = bj * 128;

  const int tid  = threadIdx.x;
  const int lane = tid & 63;
  const int w    = tid >> 6;
  const int wr   = (w >> 1) * 64;   // wave row base
  const int wc   = (w & 1) * 64;    // wave col base
  const int lrow = lane & 15;
  const int lq   = lane >> 4;

  // fragment base pointers: A frag (mi,k-step s): row i0+wr+mi*16+lrow,
  // elements [s*32 + lq*8 .. +7]  (A-operand layout: m=lane&15, k=lq*8+j)
  const unsigned short* pA[4];
  const unsigned short* pB[4];
  #pragma unroll
  for (int x = 0; x < 4; ++x) {
    pA[x] = g_fnb + (size_t)(i0 + wr + x * 16 + lrow) * DIM + lq * 8;
    pB[x] = g_fnb + (size_t)(j0 + wc + x * 16 + lrow) * DIM + lq * 8;
  }

  f32x4 acc[4][4];
  #pragma unroll
  for (int a = 0; a < 4; ++a)
    #pragma unroll
    for (int b = 0; b < 4; ++b) { acc[a][b][0]=0.f; acc[a][b][1]=0.f; acc[a][b][2]=0.f; acc[a][b][3]=0.f; }

  // two fragment register sets, alternating: distance-1 prefetch, no barriers
  s16x8 a0[4], b0[4], a1[4], b1[4];
  #pragma unroll
  for (int x = 0; x < 4; ++x) {
    a0[x] = *(const s16x8*)(pA[x]);
    b0[x] = *(const s16x8*)(pB[x]);
  }

  for (int it = 0; it < 8; ++it) {          // 8 iters x (2 half-steps of K=32)
    #pragma unroll
    for (int x = 0; x < 4; ++x) {           // prefetch half-step 2it+1
      a1[x] = *(const s16x8*)(pA[x] + 32);
      b1[x] = *(const s16x8*)(pB[x] + 32);
    }
    #pragma unroll
    for (int mi = 0; mi < 4; ++mi)
      #pragma unroll
      for (int ni = 0; ni < 4; ++ni)
        acc[mi][ni] = __builtin_amdgcn_mfma_f32_16x16x32_bf16(a0[mi], b0[ni], acc[mi][ni], 0, 0, 0);
    #pragma unroll
    for (int x = 0; x < 4; ++x) { pA[x] += 64; pB[x] += 64; }
    if (it < 7) {
      #pragma unroll
      for (int x = 0; x < 4; ++x) {         // prefetch half-step 2it+2
        a0[x] = *(const s16x8*)(pA[x]);
        b0[x] = *(const s16x8*)(pB[x]);
      }
    }
    #pragma unroll
    for (int mi = 0; mi < 4; ++mi)
      #pragma unroll
      for (int ni = 0; ni < 4; ++ni)
        acc[mi][ni] = __builtin_amdgcn_mfma_f32_16x16x32_bf16(a1[mi], b1[ni], acc[mi][ni], 0, 0, 0);
  }

  // ---- epilogue. C layout: col = lane&15 (+ni*16+wc), row = lq*4+reg (+mi*16+wr).
  // row side (always)
  #pragma unroll
  for (int mi = 0; mi < 4; ++mi) {
    #pragma unroll
    for (int r = 0; r < 4; ++r) {
      const int i  = i0 + wr + mi * 16 + lq * 4 + r;
      const float pv = g_pos[i];
      float s = 0.f; int c = 0;
      #pragma unroll
      for (int ni = 0; ni < 4; ++ni) {
        const int j = j0 + wc + ni * 16 + lrow;
        const float v = acc[mi][ni][r];
        const float e = __expf(v * INV_T);
        const bool diag = (j == i);
        s += diag ? 0.f : e;
        c += (!diag && (j != (i ^ HALF_N)) && (v > pv)) ? 1 : 0;
      }
      #pragma unroll
      for (int o = 1; o < 16; o <<= 1) {
        s += __shfl_xor(s, o, 64);
        c += __shfl_xor(c, o, 64);
      }
      if (lrow == 0) {
        atomicAdd(&g_sumexp[i], s);
        atomicAdd(&g_cnt[i], c);
      }
    }
  }

  // col side (off-diagonal only; i and j slabs disjoint -> j != i always)
  if (offdiag) {
    #pragma unroll
    for (int ni = 0; ni < 4; ++ni) {
      const int j  = j0 + wc + ni * 16 + lrow;
      const float pj = g_pos[j];
      float s = 0.f; int c = 0;
      #pragma unroll
      for (int mi = 0; mi < 4; ++mi) {
        #pragma unroll
        for (int r = 0; r < 4; ++r) {
          const int i = i0 + wr + mi * 16 + lq * 4 + r;
          const float v = acc[mi][ni][r];
          s += __expf(v * INV_T);
          c += ((i != (j ^ HALF_N)) && (v > pj)) ? 1 : 0;
        }
      }
      s += __shfl_xor(s, 16, 64); s += __shfl_xor(s, 32, 64);
      c += __shfl_xor(c, 16, 64); c += __shfl_xor(c, 32, 64);
      if (lq == 0) {
        atomicAdd(&g_sumexp[j], s);
        atomicAdd(&g_cnt[j], c);
      }
    }
  }

  // ---- last-block finalize: fold the 4-scalar reduction into this kernel ----
  __threadfence();                      // order my atomics before the counter add
  __shared__ int s_last;
  if (tid == 0) s_last = (atomicAdd(&g_done, 1) == NBLK - 1);
  __syncthreads();
  if (s_last) {
    float nll = 0.f, t1 = 0.f, t5 = 0.f, mr = 0.f;
    for (int i = tid; i < NTOT; i += 256) {
      // device-scope loads: bypass L1, read the L2/coherent-point values
      const float se = __hip_atomic_load(&g_sumexp[i], __ATOMIC_RELAXED,
                                         __HIP_MEMORY_SCOPE_AGENT);
      const int  c  = __hip_atomic_load(&g_cnt[i], __ATOMIC_RELAXED,
                                        __HIP_MEMORY_SCOPE_AGENT);
      nll += -g_pos[i] * INV_T + logf(se);
      t1 += (c == 0) ? 1.f : 0.f;
      t5 += (c < 5) ? 1.f : 0.f;
      mr += (float)c;
    }
    #pragma unroll
    for (int o = 32; o >= 1; o >>= 1) {
      nll += __shfl_xor(nll, o, 64);
      t1  += __shfl_xor(t1, o, 64);
      t5  += __shfl_xor(t5, o, 64);
      mr  += __shfl_xor(mr, o, 64);
    }
    __shared__ float red[4][4];
    if ((tid & 63) == 0) {
      red[tid >> 6][0] = nll; red[tid >> 6][1] = t1;
      red[tid >> 6][2] = t5;  red[tid >> 6][3] = mr;
    }
    __syncthreads();
    if (tid == 0) {
      float a = 0.f, b = 0.f, c = 0.f, d = 0.f;
      for (int k = 0; k < 4; ++k) { a += red[k][0]; b += red[k][1]; c += red[k][2]; d += red[k][3]; }
      out[0] = a / (float)NTOT;
      out[1] = b / (float)NTOT;
      out[2] = c / (float)NTOT;
      out[3] = 1.f + d / (float)NTOT;
    }
  }
}

extern "C" void kernel_launch(void* const* d_in, const int* in_sizes, int n_in,
                              void* d_out, int out_size, void* d_ws, size_t ws_size,
                              hipStream_t stream) {
  const float* f1 = (const float*)d_in[0];
  const float* f2 = (const float*)d_in[1];
  float* out = (float*)d_out;

  knorm<<<dim3(2048), dim3(256), 0, stream>>>(f1, f2);
  kmain<<<dim3(NBLK), dim3(256), 0, stream>>>(out);
}

// Round 7
// 261.676 us; speedup vs baseline: 1.6623x; 1.6623x over previous
//
#include <hip/hip_runtime.h>
#include <math.h>
#include <stdint.h>

#define NTOT   8192
#define HALF_N 4096
#define DIM    512
#define INV_T  14.2857142857142857f   // 1/0.07
#define NBLK   544                    // triangular supertile grid (128r x 512c)
#define LDST   40                     // LDS row stride in shorts: 32 + 8 pad
                                      // (80 B rows -> 2 lanes/bank = free, 16B-aligned)

using s16x8 = __attribute__((ext_vector_type(8))) short;
using f32x4 = __attribute__((ext_vector_type(4))) float;

// Scratch in static device globals (fully rewritten every call; no d_ws use).
__device__ unsigned short g_fnb[NTOT * DIM];   // normalized bf16 matrix, 8 MB
__device__ float g_pos[NTOT];
__device__ float g_sumexp[NTOT];
__device__ int   g_cnt[NTOT];
__device__ int   g_done;                       // last-block-finalize counter

__device__ __forceinline__ float bf2f(unsigned short u) {
  union { unsigned int i; float f; } v; v.i = ((unsigned int)u) << 16; return v.f;
}
__device__ __forceinline__ unsigned short f2bf(float x) {
  union { float f; unsigned int i; } v; v.f = x;
  unsigned int u = v.i;
  return (unsigned short)((u + 0x7FFFu + ((u >> 16) & 1u)) >> 16);
}

// ---------------- kernel 1: normalize pairs -> bf16, pos, zero stats ----------------
__global__ __launch_bounds__(256) void knorm(const float* __restrict__ f1,
                                             const float* __restrict__ f2) {
  const int tid  = threadIdx.x;
  const int wv   = tid >> 6;
  const int pi   = wv >> 1;            // pair within block
  const int half = wv & 1;             // 0: f1 row, 1: f2 row
  const int lane = tid & 63;
  const int b    = blockIdx.x * 2 + pi;
  const int row  = b + half * HALF_N;

  if (blockIdx.x == 0 && tid == 0) g_done = 0;
  if (tid < 4) {                       // zero the 4 stat rows this block owns
    const int r = blockIdx.x * 2 + (tid & 1) + (tid >> 1) * HALF_N;
    g_sumexp[r] = 0.f; g_cnt[r] = 0;
  }

  const float* src = (half == 0) ? (f1 + (size_t)b * DIM) : (f2 + (size_t)b * DIM);
  float4 v0 = ((const float4*)src)[lane];
  float4 v1 = ((const float4*)src)[lane + 64];
  float ss = v0.x*v0.x + v0.y*v0.y + v0.z*v0.z + v0.w*v0.w
           + v1.x*v1.x + v1.y*v1.y + v1.z*v1.z + v1.w*v1.w;
  #pragma unroll
  for (int o = 32; o >= 1; o >>= 1) ss += __shfl_xor(ss, o, 64);
  const float sc = 1.0f / fmaxf(sqrtf(ss), 1e-8f);
  ushort4 h0, h1;
  h0.x = f2bf(v0.x * sc); h0.y = f2bf(v0.y * sc);
  h0.z = f2bf(v0.z * sc); h0.w = f2bf(v0.w * sc);
  h1.x = f2bf(v1.x * sc); h1.y = f2bf(v1.y * sc);
  h1.z = f2bf(v1.z * sc); h1.w = f2bf(v1.w * sc);
  ushort4* dst = (ushort4*)(g_fnb + (size_t)row * DIM);
  dst[lane]      = h0;
  dst[lane + 64] = h1;

  // pos[b] = <fn_b, fn_{b+4096}> on the same bf16 values the GEMM uses
  __shared__ ushort4 sh[2][64][2];
  if (half == 1) { sh[pi][lane][0] = h0; sh[pi][lane][1] = h1; }
  __syncthreads();
  if (half == 0) {
    const ushort4 p0 = sh[pi][lane][0], p1 = sh[pi][lane][1];
    float s = bf2f(h0.x)*bf2f(p0.x) + bf2f(h0.y)*bf2f(p0.y)
            + bf2f(h0.z)*bf2f(p0.z) + bf2f(h0.w)*bf2f(p0.w)
            + bf2f(h1.x)*bf2f(p1.x) + bf2f(h1.y)*bf2f(p1.y)
            + bf2f(h1.z)*bf2f(p1.z) + bf2f(h1.w)*bf2f(p1.w);
    #pragma unroll
    for (int o = 32; o >= 1; o >>= 1) s += __shfl_xor(s, o, 64);
    if (lane == 0) { g_pos[b] = s; g_pos[b + HALF_N] = s; }
  }
}

// ---------------- kernel 2: triangular supertile GEMM + reductions + finalize ------
// Supertile = 128 rows (bi) x 4 col-tiles (cj covers bj = 4cj..4cj+3), only
// tiles with bj >= bi computed. 544 blocks, R2-like work per block (~63 MFLOP).
// BK=32, LDS staging with stride-40 padding (2-way bank aliasing = free),
// named-reg distance-1 prefetch (16 VGPRs, spill-proof), epilogue per j-tile.
__global__ __launch_bounds__(256, 3) void kmain(float* __restrict__ out) {
  __shared__ unsigned short As[128 * LDST];
  __shared__ unsigned short Bs[128 * LDST];

  // supertile decode: groups by q = bi>>2; group q has 4 rows x (16-q) chunks
  int t = blockIdx.x, q = 0;
  while (t >= 4 * (16 - q)) { t -= 4 * (16 - q); ++q; }
  const int m   = 16 - q;
  const int bi  = 4 * q + t / m;
  const int cj  = q + t % m;
  const int jlo = max(bi, 4 * cj);
  const int jhi = 4 * cj + 3;
  const int nsteps = (jhi - jlo + 1) << 4;   // 16 kt-steps per j-tile

  const int tid  = threadIdx.x;
  const int lane = tid & 63;
  const int w    = tid >> 6;
  const int wr   = (w >> 1) * 64;   // wave row base
  const int wc   = (w & 1) * 64;    // wave col base
  const int lrow = lane & 15;
  const int lq   = lane >> 4;
  const int i0   = bi * 128;

  // staging map: thread covers rows (tid>>2) and (tid>>2)+64, col block tid&3
  const int srow = tid >> 2;
  const int scb  = tid & 3;
  const unsigned short* Ag = g_fnb + (size_t)(i0 + srow) * DIM + scb * 8;
  unsigned short* Aw = &As[srow * LDST + scb * 8];
  unsigned short* Bw = &Bs[srow * LDST + scb * 8];

  f32x4 acc[4][4];
  #pragma unroll
  for (int a = 0; a < 4; ++a)
    #pragma unroll
    for (int b = 0; b < 4; ++b) { acc[a][b][0]=0.f; acc[a][b][1]=0.f; acc[a][b][2]=0.f; acc[a][b][3]=0.f; }

  // prologue: prefetch step 0 into named regs
  int4 pa0, pa1, pb0, pb1;
  {
    const unsigned short* Bg = g_fnb + (size_t)(jlo * 128 + srow) * DIM + scb * 8;
    pa0 = *(const int4*)(Ag);
    pa1 = *(const int4*)(Ag + (size_t)64 * DIM);
    pb0 = *(const int4*)(Bg);
    pb1 = *(const int4*)(Bg + (size_t)64 * DIM);
  }

  for (int s = 0; s < nsteps; ++s) {
    const int jt = jlo + (s >> 4);

    __syncthreads();                       // prev step's LDS reads done
    *(int4*)(Aw)              = pa0;
    *(int4*)(Aw + 64 * LDST)  = pa1;
    *(int4*)(Bw)              = pb0;
    *(int4*)(Bw + 64 * LDST)  = pb1;
    __syncthreads();                       // step s tile visible

    if (s + 1 < nsteps) {                  // prefetch step s+1 under the MFMAs
      const int s2  = s + 1;
      const int jt2 = jlo + (s2 >> 4);
      const int kb2 = (s2 & 15) * 32;
      const unsigned short* Bg2 = g_fnb + (size_t)(jt2 * 128 + srow) * DIM + scb * 8;
      pa0 = *(const int4*)(Ag + kb2);
      pa1 = *(const int4*)(Ag + (size_t)64 * DIM + kb2);
      pb0 = *(const int4*)(Bg2 + kb2);
      pb1 = *(const int4*)(Bg2 + (size_t)64 * DIM + kb2);
    }

    // fragments: A row = wr+mi*16+lrow, k = lq*8..+7 (verified layout)
    s16x8 af[4], bf[4];
    #pragma unroll
    for (int mi = 0; mi < 4; ++mi)
      af[mi] = *(const s16x8*)(&As[(wr + mi * 16 + lrow) * LDST + lq * 8]);
    #pragma unroll
    for (int ni = 0; ni < 4; ++ni)
      bf[ni] = *(const s16x8*)(&Bs[(wc + ni * 16 + lrow) * LDST + lq * 8]);
    #pragma unroll
    for (int mi = 0; mi < 4; ++mi)
      #pragma unroll
      for (int ni = 0; ni < 4; ++ni)
        acc[mi][ni] = __builtin_amdgcn_mfma_f32_16x16x32_bf16(af[mi], bf[ni], acc[mi][ni], 0, 0, 0);

    if ((s & 15) == 15) {
      // ---- epilogue for j-tile jt. C: col = lane&15, row = lq*4+reg (verified).
      const int j0 = jt * 128;
      const bool offd = (jt != bi);

      #pragma unroll
      for (int mi = 0; mi < 4; ++mi) {          // row side (always)
        #pragma unroll
        for (int r = 0; r < 4; ++r) {
          const int i  = i0 + wr + mi * 16 + lq * 4 + r;
          const float pv = g_pos[i];
          float sx = 0.f; int c = 0;
          #pragma unroll
          for (int ni = 0; ni < 4; ++ni) {
            const int j = j0 + wc + ni * 16 + lrow;
            const float v = acc[mi][ni][r];
            const float e = __expf(v * INV_T);
            const bool diag = (j == i);
            sx += diag ? 0.f : e;
            c += (!diag && (j != (i ^ HALF_N)) && (v > pv)) ? 1 : 0;
          }
          #pragma unroll
          for (int o = 1; o < 16; o <<= 1) {
            sx += __shfl_xor(sx, o, 64);
            c  += __shfl_xor(c, o, 64);
          }
          if (lrow == 0) {
            atomicAdd(&g_sumexp[i], sx);
            atomicAdd(&g_cnt[i], c);
          }
        }
      }

      if (offd) {                               // col side (disjoint slabs)
        #pragma unroll
        for (int ni = 0; ni < 4; ++ni) {
          const int j  = j0 + wc + ni * 16 + lrow;
          const float pj = g_pos[j];
          float sx = 0.f; int c = 0;
          #pragma unroll
          for (int mi = 0; mi < 4; ++mi) {
            #pragma unroll
            for (int r = 0; r < 4; ++r) {
              const int i = i0 + wr + mi * 16 + lq * 4 + r;
              const float v = acc[mi][ni][r];
              sx += __expf(v * INV_T);
              c += ((i != (j ^ HALF_N)) && (v > pj)) ? 1 : 0;
            }
          }
          sx += __shfl_xor(sx, 16, 64); sx += __shfl_xor(sx, 32, 64);
          c  += __shfl_xor(c, 16, 64);  c  += __shfl_xor(c, 32, 64);
          if (lq == 0) {
            atomicAdd(&g_sumexp[j], sx);
            atomicAdd(&g_cnt[j], c);
          }
        }
      }

      #pragma unroll
      for (int a = 0; a < 4; ++a)               // reset acc for next j-tile
        #pragma unroll
        for (int b = 0; b < 4; ++b) { acc[a][b][0]=0.f; acc[a][b][1]=0.f; acc[a][b][2]=0.f; acc[a][b][3]=0.f; }
    }
  }

  // ---- last-block finalize (R6-validated) ----
  __threadfence();
  __shared__ int s_last;
  if (tid == 0) s_last = (atomicAdd(&g_done, 1) == NBLK - 1);
  __syncthreads();
  if (s_last) {
    float nll = 0.f, t1 = 0.f, t5 = 0.f, mr = 0.f;
    for (int i = tid; i < NTOT; i += 256) {
      const float se = __hip_atomic_load(&g_sumexp[i], __ATOMIC_RELAXED,
                                         __HIP_MEMORY_SCOPE_AGENT);
      const int  c  = __hip_atomic_load(&g_cnt[i], __ATOMIC_RELAXED,
                                        __HIP_MEMORY_SCOPE_AGENT);
      nll += -g_pos[i] * INV_T + logf(se);
      t1 += (c == 0) ? 1.f : 0.f;
      t5 += (c < 5) ? 1.f : 0.f;
      mr += (float)c;
    }
    #pragma unroll
    for (int o = 32; o >= 1; o >>= 1) {
      nll += __shfl_xor(nll, o, 64);
      t1  += __shfl_xor(t1, o, 64);
      t5  += __shfl_xor(t5, o, 64);
      mr  += __shfl_xor(mr, o, 64);
    }
    __shared__ float red[4][4];
    if ((tid & 63) == 0) {
      red[tid >> 6][0] = nll; red[tid >> 6][1] = t1;
      red[tid >> 6][2] = t5;  red[tid >> 6][3] = mr;
    }
    __syncthreads();
    if (tid == 0) {
      float a = 0.f, b = 0.f, c = 0.f, d = 0.f;
      for (int k = 0; k < 4; ++k) { a += red[k][0]; b += red[k][1]; c += red[k][2]; d += red[k][3]; }
      out[0] = a / (float)NTOT;
      out[1] = b / (float)NTOT;
      out[2] = c / (float)NTOT;
      out[3] = 1.f + d / (float)NTOT;
    }
  }
}

extern "C" void kernel_launch(void* const* d_in, const int* in_sizes, int n_in,
                              void* d_out, int out_size, void* d_ws, size_t ws_size,
                              hipStream_t stream) {
  const float* f1 = (const float*)d_in[0];
  const float* f2 = (const float*)d_in[1];
  float* out = (float*)d_out;

  knorm<<<dim3(2048), dim3(256), 0, stream>>>(f1, f2);
  kmain<<<dim3(NBLK), dim3(256), 0, stream>>>(out);
}